// Round 3
// baseline (178.530 us; speedup 1.0000x reference)
//
#include <hip/hip_runtime.h>

#define MT 64   // number of event types M
#define KK 4    // number of kernels K
#define NG 64   // scan groups

// ---------- helpers ----------
__device__ __forceinline__ float wredf(float v) {
  #pragma unroll
  for (int off = 32; off > 0; off >>= 1) v += __shfl_xor(v, off, 64);
  return v;
}
__device__ __forceinline__ double wredd(double v) {
  #pragma unroll
  for (int off = 32; off > 0; off >>= 1) v += __shfl_xor(v, off, 64);
  return v;
}
// T arrives as a 1-element array; reference does jnp.float32(T).
__device__ __forceinline__ float parse_T(const int* Tp) {
  int v = *Tp;
  if (v >= 1 && v <= 1000000000) return (float)v;
  return __int_as_float(v);
}

// ---------- K1: decay factors d4[i], compensator type-bins W_b, AT4g table, counter reset ----------
// Each block handles 1024 events. W_b[m*4+k] = sum_{j in blk, m_j=m} (1 - exp(-gamma_k (T - t_j)))
__global__ __launch_bounds__(256) void k_pre(
    const float* __restrict__ t, const int* __restrict__ mi,
    const float* __restrict__ alpha, const float* __restrict__ gamma,
    const int* __restrict__ Tp,
    float4* __restrict__ d4, float* __restrict__ Wb, float4* __restrict__ AT4g,
    int* __restrict__ counter, int N)
{
  __shared__ float W[MT*KK];
  const int tid = threadIdx.x;
  W[tid] = 0.f;
  __syncthreads();
  const float g0=gamma[0], g1=gamma[1], g2=gamma[2], g3=gamma[3];
  const float T = parse_T(Tp);
  const int base = blockIdx.x * 1024;
  #pragma unroll
  for (int j = 0; j < 4; ++j) {
    const int i = base + j*256 + tid;
    if (i < MT*MT) {                      // blocks 0..3 also emit the gamma-scaled table
      float a0 = alpha[i],            a1 = alpha[MT*MT + i];
      float a2 = alpha[2*MT*MT + i],  a3 = alpha[3*MT*MT + i];
      AT4g[i] = make_float4(g0*a0, g1*a1, g2*a2, g3*a3);
    }
    if (i < N) {
      float ti = t[i];
      float tp = (i > 0) ? t[i-1] : ti;
      float dt = ti - tp;
      d4[i] = make_float4(__expf(-g0*dt), __expf(-g1*dt),
                          __expf(-g2*dt), __expf(-g3*dt));
      int m = mi[i];
      float x = T - ti;
      atomicAdd(&W[(m<<2)+0], 1.f-__expf(-g0*x));
      atomicAdd(&W[(m<<2)+1], 1.f-__expf(-g1*x));
      atomicAdd(&W[(m<<2)+2], 1.f-__expf(-g2*x));
      atomicAdd(&W[(m<<2)+3], 1.f-__expf(-g3*x));
    }
  }
  if (blockIdx.x == 0 && tid == 0) *counter = 0;   // reset every call (deterministic)
  __syncthreads();
  Wb[(size_t)blockIdx.x*256 + tid] = W[tid];
}

// ---------- K2: block-local q-space state + block decay factor (no LDS) ----------
// q_k[n] = sum_{j in block} exp(-gamma_k*(t_ref - t_j)) * gamma_k*alpha[k][m_j][n]
__global__ __launch_bounds__(256) void k_phase1(
    const float* __restrict__ t, const int* __restrict__ mi,
    const float4* __restrict__ d4, const float4* __restrict__ AT4g,
    const float* __restrict__ gamma,
    float* __restrict__ P, float* __restrict__ decf, int N, int B)
{
  const int tid = threadIdx.x, lane = tid & 63;
  int b = blockIdx.x*4 + (tid >> 6);
  b = __builtin_amdgcn_readfirstlane(b);
  const int s0 = b*B, e0 = min(N, s0+B);
  float q0=0.f, q1=0.f, q2=0.f, q3=0.f;
  for (int i = s0; i < e0; ++i) {
    float4 d = d4[i];                       // wave-uniform -> scalar load
    int m = mi[i];
    float4 a = AT4g[(m<<6) + lane];         // coalesced 1KB/wave, L1/L2-hit
    q0 = fmaf(q0, d.x, a.x); q1 = fmaf(q1, d.y, a.y);
    q2 = fmaf(q2, d.z, a.z); q3 = fmaf(q3, d.w, a.w);
  }
  float* Pb = P + (size_t)b*256;
  Pb[lane]=q0; Pb[64+lane]=q1; Pb[128+lane]=q2; Pb[192+lane]=q3;
  int last  = max(e0-1, 0);
  int plast = min(max(s0-1, 0), N-1);
  float dtb = t[last] - t[plast];
  if (lane < KK) decf[b*4 + lane] = __expf(-gamma[lane]*dtb);
}

// ---------- K3: sequential scan within each group of blocks ----------
__global__ __launch_bounds__(256) void k_scan_group(
    const float* __restrict__ P, const float* __restrict__ decf,
    float* __restrict__ Cl, float* __restrict__ Ag, int GB)
{
  const int tid = threadIdx.x;
  const int g = blockIdx.x;
  const int k = tid >> 6;
  float c = 0.f;
  const int bend = (g+1)*GB;
  for (int b = g*GB; b < bend; ++b) {
    Cl[(size_t)b*256 + tid] = c;            // carry INTO block b (group-local)
    c = fmaf(c, decf[b*4 + k], P[(size_t)b*256 + tid]);
  }
  Ag[(size_t)g*256 + tid] = c;
}

// ---------- K4: scan the NG group aggregates ----------
__global__ __launch_bounds__(256) void k_scan_top(
    const float* __restrict__ t, const float* __restrict__ gamma,
    const float* __restrict__ Ag, float* __restrict__ GP,
    int N, int B, int GB)
{
  const int tid = threadIdx.x;
  const float gk = gamma[tid >> 6];
  float c = 0.f;
  float tprev = t[0];
  for (int g = 0; g < NG; ++g) {
    GP[(size_t)g*256 + tid] = c;
    int last = min((g+1)*GB*B, N) - 1;
    float tg = t[last];
    c = fmaf(c, __expf(-gk*(tg - tprev)), Ag[(size_t)g*256 + tid]);
    tprev = tg;
  }
}

// ---------- K5: per-event intensity with carried q-state + fused final reduction ----------
__global__ __launch_bounds__(256) void k_phase3(
    const float* __restrict__ t, const int* __restrict__ mi,
    const float* __restrict__ alpha, const float* __restrict__ gamma,
    const float* __restrict__ mu,
    const float4* __restrict__ d4, const float4* __restrict__ AT4g,
    const float* __restrict__ Cl, const float* __restrict__ GP,
    const float* __restrict__ Wb, int nwb,
    float* __restrict__ npt, int* __restrict__ counter, const int* __restrict__ Tp,
    float* __restrict__ out, int N, int B, int NB, int GB)
{
  const int tid = threadIdx.x, lane = tid & 63;
  int b = blockIdx.x*4 + (tid >> 6);
  b = __builtin_amdgcn_readfirstlane(b);
  const int s0 = b*B, e0 = min(N, s0+B);
  float nll = 0.f;
  {
    const int g = b / GB;
    const int plast = max(s0-1, 0);
    const int glast = max(g*GB*B - 1, 0);
    const float tp0 = t[plast];
    const float dfx = tp0 - t[glast];
    const float g0=gamma[0], g1=gamma[1], g2=gamma[2], g3=gamma[3];
    const float* Clb = Cl + (size_t)b*256;
    const float* GPg = GP + (size_t)g*256;
    float q0 = fmaf(GPg[lane],      __expf(-g0*dfx), Clb[lane]);
    float q1 = fmaf(GPg[64+lane],   __expf(-g1*dfx), Clb[64+lane]);
    float q2 = fmaf(GPg[128+lane],  __expf(-g2*dfx), Clb[128+lane]);
    float q3 = fmaf(GPg[192+lane],  __expf(-g3*dfx), Clb[192+lane]);
    const float mul = mu[lane];
    float acc = 0.f;                        // sum of log2(lam) on lane m_i
    for (int i = s0; i < e0; ++i) {
      float4 d = d4[i];                     // wave-uniform
      int m = mi[i];
      float s = q0*d.x; s = fmaf(q1,d.y,s); s = fmaf(q2,d.z,s); s = fmaf(q3,d.w,s);
      float lg = __log2f(s + mul);          // valid on every lane (all positive)
      acc += (lane == m) ? lg : 0.f;
      float4 a = AT4g[(m<<6) + lane];
      q0 = fmaf(q0, d.x, a.x); q1 = fmaf(q1, d.y, a.y);
      q2 = fmaf(q2, d.z, a.z); q3 = fmaf(q3, d.w, a.w);
    }
    nll = wredf(acc);
  }
  if (lane == 0) npt[b] = nll;

  // ---- last-block-done final reduction ----
  __threadfence();
  __syncthreads();
  __shared__ int lastFlag;
  if (tid == 0) {
    int old = atomicAdd(counter, 1);        // device-scope
    lastFlag = (old == (int)gridDim.x - 1);
  }
  __syncthreads();
  if (!lastFlag) return;
  __threadfence();                          // acquire: see all npt/Wb writes

  double sn = 0.0;
  for (int i2 = tid; i2 < NB; i2 += 256) sn += (double)npt[i2];
  double Wt = 0.0;                          // W[m,k] total, tid = (m<<2)|k
  for (int blk = 0; blk < nwb; ++blk) Wt += (double)Wb[(size_t)blk*256 + tid];
  const int m_ = tid >> 2, k_ = tid & 3;
  const float4* arow = (const float4*)(alpha + (size_t)k_*MT*MT + m_*MT);
  float as = 0.f;                           // asum[k_, m_]
  #pragma unroll
  for (int j = 0; j < MT/4; ++j) { float4 v = arow[j]; as += (v.x+v.y)+(v.z+v.w); }
  double sc = (double)as * Wt;
  double sm = (tid < MT) ? (double)mu[tid] : 0.0;
  sc = wredd(sc); sn = wredd(sn); sm = wredd(sm);
  __shared__ double s3[3][4];
  const int wv = tid >> 6;
  if (lane == 0) { s3[0][wv]=sc; s3[1][wv]=sn; s3[2][wv]=sm; }
  __syncthreads();
  if (tid == 0) {
    double C = s3[0][0]+s3[0][1]+s3[0][2]+s3[0][3];
    double L = (s3[1][0]+s3[1][1]+s3[1][2]+s3[1][3]) * 0.6931471805599453; // ln2
    double M = s3[2][0]+s3[2][1]+s3[2][2]+s3[2][3];
    double T = (double)parse_T(Tp);
    out[0] = (float)((C + T*M - L) / (double)N);
  }
}

extern "C" void kernel_launch(void* const* d_in, const int* in_sizes, int n_in,
                              void* d_out, int out_size, void* d_ws, size_t ws_size,
                              hipStream_t stream)
{
  const float* mu    = (const float*)d_in[0];
  const float* alpha = (const float*)d_in[1];   // (K, M, M)
  const float* gamma = (const float*)d_in[2];   // (K,)
  const float* t     = (const float*)d_in[3];   // (N,)
  const int*   mi    = (const int*)d_in[4];     // (N,) int32
  const int*   Tp    = (const int*)d_in[5];     // scalar
  const int N    = in_sizes[3];
  const int NDW2 = (N + 1023) / 1024;

  // floats needed: d4(N*4) + AT4g(16384) + P(NB*256) + Cl(NB*256) + decf(NB*4)
  //                + Ag(NG*256) + GP(NG*256) + Wb(NDW2*256) + npt(NB) + counter(1)
  auto needF = [&](int nb) -> size_t {
    return (size_t)N*4 + MT*MT*4 + (size_t)nb*517 + 2*(size_t)NG*256
         + (size_t)NDW2*256 + 8;
  };
  int NB = 4096;
  while (NB > 128 && needF(NB)*4 > ws_size) NB >>= 1;
  const int B  = (N + NB - 1) / NB;
  const int GB = NB / NG;

  float*  d4f   = (float*)d_ws;                       // N*4
  float*  AT4gf = d4f   + (size_t)N*4;                // 16384
  float*  P     = AT4gf + MT*MT*4;                    // NB*256
  float*  Cl    = P     + (size_t)NB*256;             // NB*256
  float*  dfc   = Cl    + (size_t)NB*256;             // NB*4
  float*  Ag    = dfc   + (size_t)NB*4;               // NG*256
  float*  GP    = Ag    + (size_t)NG*256;             // NG*256
  float*  Wb    = GP    + (size_t)NG*256;             // NDW2*256
  float*  npt   = Wb    + (size_t)NDW2*256;           // NB
  int*    cnt   = (int*)(npt + NB);                   // 1
  float4* d4    = (float4*)d4f;
  float4* AT4g  = (float4*)AT4gf;

  k_pre       <<<NDW2, 256, 0, stream>>>(t, mi, alpha, gamma, Tp, d4, Wb, AT4g, cnt, N);
  k_phase1    <<<NB/4, 256, 0, stream>>>(t, mi, d4, AT4g, gamma, P, dfc, N, B);
  k_scan_group<<<NG,   256, 0, stream>>>(P, dfc, Cl, Ag, GB);
  k_scan_top  <<<1,    256, 0, stream>>>(t, gamma, Ag, GP, N, B, GB);
  k_phase3    <<<NB/4, 256, 0, stream>>>(t, mi, alpha, gamma, mu, d4, AT4g, Cl, GP,
                                         Wb, NDW2, npt, cnt, Tp, (float*)d_out,
                                         N, B, NB, GB);
}

// Round 4
// 103.745 us; speedup vs baseline: 1.7208x; 1.7208x over previous
//
#include <hip/hip_runtime.h>

#define MT 64   // number of event types M
#define KK 4    // number of kernels K
#define GBC 16  // blocks per scan group

// ---------- helpers ----------
__device__ __forceinline__ float wredf(float v) {
  #pragma unroll
  for (int off = 32; off > 0; off >>= 1) v += __shfl_xor(v, off, 64);
  return v;
}
__device__ __forceinline__ double wredd(double v) {
  #pragma unroll
  for (int off = 32; off > 0; off >>= 1) v += __shfl_xor(v, off, 64);
  return v;
}
// T arrives as a 1-element array; reference does jnp.float32(T).
__device__ __forceinline__ float parse_T(const int* Tp) {
  int v = *Tp;
  if (v >= 1 && v <= 1000000000) return (float)v;
  return __int_as_float(v);
}

// ---------- K1: d4 + compensator partials (thread/event) + block-local q-scan (wave/block) ----------
__global__ __launch_bounds__(512, 4) void k_phase1(
    const float* __restrict__ t, const int* __restrict__ mi,
    const float* __restrict__ alpha, const float* __restrict__ gamma,
    const int* __restrict__ Tp,
    float4* __restrict__ d4, float4* __restrict__ P4, float4* __restrict__ decf4,
    float* __restrict__ compP, int N, int B, int CH)
{
  __shared__ float4 AT4[MT*MT];   // AT4[m*64+n] = {gamma_k * alpha[k][m][n]}
  __shared__ float4 asumS[MT];    // asumS[m] = {sum_n alpha[k][m][n]}
  __shared__ float red[8];
  const int tid = threadIdx.x;
  const float g0=gamma[0], g1=gamma[1], g2=gamma[2], g3=gamma[3];
  #pragma unroll
  for (int idx = tid; idx < MT*MT; idx += 512) {
    float a0=alpha[idx],         a1=alpha[MT*MT+idx];
    float a2=alpha[2*MT*MT+idx], a3=alpha[3*MT*MT+idx];
    AT4[idx] = make_float4(g0*a0, g1*a1, g2*a2, g3*a3);
  }
  if (tid < MT*KK) {
    const int m = tid >> 2, k = tid & 3;
    const float4* row = (const float4*)(alpha + (size_t)k*MT*MT + m*MT);
    float s = 0.f;
    #pragma unroll
    for (int j = 0; j < MT/4; ++j) { float4 v = row[j]; s += (v.x+v.y)+(v.z+v.w); }
    ((float*)asumS)[(m<<2)+k] = s;
  }
  __syncthreads();

  // --- thread-per-event: decay factors + compensator ---
  const float T = parse_T(Tp);
  float comp = 0.f;
  {
    const int i0 = blockIdx.x * CH;
    const int i1 = min(N, i0 + CH);
    for (int i = i0 + tid; i < i1; i += 512) {
      float ti = t[i];
      float tp = (i > 0) ? t[i-1] : ti;
      float dt = ti - tp;
      d4[i] = make_float4(__expf(-g0*dt), __expf(-g1*dt),
                          __expf(-g2*dt), __expf(-g3*dt));
      int m = mi[i];
      float x = T - ti;
      float4 as = asumS[m];
      comp = fmaf(as.x, 1.f-__expf(-g0*x), comp);
      comp = fmaf(as.y, 1.f-__expf(-g1*x), comp);
      comp = fmaf(as.z, 1.f-__expf(-g2*x), comp);
      comp = fmaf(as.w, 1.f-__expf(-g3*x), comp);
    }
  }
  comp = wredf(comp);
  if ((tid & 63) == 0) red[tid >> 6] = comp;

  // --- wave-per-block local scan (own exps; d4 of other chunks not yet visible) ---
  const int lane = tid & 63;
  int b = __builtin_amdgcn_readfirstlane((int)blockIdx.x*8 + (tid >> 6));
  const int s0 = b*B, e0 = min(N, s0+B);
  float4 q = make_float4(0.f,0.f,0.f,0.f);
  if (s0 < e0) {
    float tprev = t[s0];
    int i = s0;
    const int e4 = s0 + ((e0 - s0) & ~3);
    for (; i < e4; i += 4) {
      float tA=t[i], tB=t[i+1], tC=t[i+2], tD=t[i+3];
      int   mA=mi[i], mB=mi[i+1], mC=mi[i+2], mD=mi[i+3];
      float4 aA=AT4[(mA<<6)+lane], aB=AT4[(mB<<6)+lane];
      float4 aC=AT4[(mC<<6)+lane], aD=AT4[(mD<<6)+lane];
      float dtA=tA-tprev, dtB=tB-tA, dtC=tC-tB, dtD=tD-tC; tprev=tD;
      float4 dA=make_float4(__expf(-g0*dtA),__expf(-g1*dtA),__expf(-g2*dtA),__expf(-g3*dtA));
      q.x=fmaf(q.x,dA.x,aA.x); q.y=fmaf(q.y,dA.y,aA.y);
      q.z=fmaf(q.z,dA.z,aA.z); q.w=fmaf(q.w,dA.w,aA.w);
      float4 dB=make_float4(__expf(-g0*dtB),__expf(-g1*dtB),__expf(-g2*dtB),__expf(-g3*dtB));
      q.x=fmaf(q.x,dB.x,aB.x); q.y=fmaf(q.y,dB.y,aB.y);
      q.z=fmaf(q.z,dB.z,aB.z); q.w=fmaf(q.w,dB.w,aB.w);
      float4 dC=make_float4(__expf(-g0*dtC),__expf(-g1*dtC),__expf(-g2*dtC),__expf(-g3*dtC));
      q.x=fmaf(q.x,dC.x,aC.x); q.y=fmaf(q.y,dC.y,aC.y);
      q.z=fmaf(q.z,dC.z,aC.z); q.w=fmaf(q.w,dC.w,aC.w);
      float4 dD=make_float4(__expf(-g0*dtD),__expf(-g1*dtD),__expf(-g2*dtD),__expf(-g3*dtD));
      q.x=fmaf(q.x,dD.x,aD.x); q.y=fmaf(q.y,dD.y,aD.y);
      q.z=fmaf(q.z,dD.z,aD.z); q.w=fmaf(q.w,dD.w,aD.w);
    }
    for (; i < e0; ++i) {
      float ti = t[i]; int m = mi[i];
      float dt = ti - tprev; tprev = ti;
      float4 a = AT4[(m<<6)+lane];
      float4 d = make_float4(__expf(-g0*dt),__expf(-g1*dt),__expf(-g2*dt),__expf(-g3*dt));
      q.x=fmaf(q.x,d.x,a.x); q.y=fmaf(q.y,d.y,a.y);
      q.z=fmaf(q.z,d.z,a.z); q.w=fmaf(q.w,d.w,a.w);
    }
  }
  P4[(size_t)b*64 + lane] = q;
  {
    int last  = max(e0-1, 0);
    int plast = min(max(s0-1, 0), N-1);
    float dtb = t[last] - t[plast];
    if (lane == 0)
      decf4[b] = make_float4(__expf(-g0*dtb),__expf(-g1*dtb),
                             __expf(-g2*dtb),__expf(-g3*dtb));
  }
  __syncthreads();
  if (tid == 0) {
    float c = 0.f;
    #pragma unroll
    for (int j = 0; j < 8; ++j) c += red[j];
    compP[blockIdx.x] = c;
  }
}

// ---------- K2: group scan (wave per group of GBC blocks), exp-free via decay products ----------
__global__ __launch_bounds__(256) void k_scan(
    const float4* __restrict__ P4, const float4* __restrict__ decf4,
    float4* __restrict__ Cl4, float4* __restrict__ Dc4,
    float4* __restrict__ Ag4, float4* __restrict__ gdec4)
{
  const int lane = threadIdx.x & 63;
  int g = __builtin_amdgcn_readfirstlane((int)blockIdx.x*4 + (threadIdx.x >> 6));
  float4 c  = make_float4(0.f,0.f,0.f,0.f);
  float4 dp = make_float4(1.f,1.f,1.f,1.f);
  const int b0 = g*GBC;
  #pragma unroll 4
  for (int j = 0; j < GBC; ++j) {
    const int b = b0 + j;
    Cl4[(size_t)b*64 + lane] = c;
    if (lane == 0) Dc4[b] = dp;
    float4 df = decf4[b];                   // uniform
    float4 p  = P4[(size_t)b*64 + lane];
    c.x = fmaf(c.x, df.x, p.x); c.y = fmaf(c.y, df.y, p.y);
    c.z = fmaf(c.z, df.z, p.z); c.w = fmaf(c.w, df.w, p.w);
    dp.x *= df.x; dp.y *= df.y; dp.z *= df.z; dp.w *= df.w;
  }
  Ag4[(size_t)g*64 + lane] = c;
  if (lane == 0) gdec4[g] = dp;
}

// ---------- K3: scan the NG group aggregates (single wave) ----------
__global__ __launch_bounds__(64) void k_scan_top(
    const float4* __restrict__ Ag4, const float4* __restrict__ gdec4,
    float4* __restrict__ GP4, int NG)
{
  const int lane = threadIdx.x;
  float4 c = make_float4(0.f,0.f,0.f,0.f);
  for (int g = 0; g < NG; ++g) {
    GP4[(size_t)g*64 + lane] = c;
    float4 gd = gdec4[g];                   // uniform
    float4 a  = Ag4[(size_t)g*64 + lane];
    c.x = fmaf(c.x, gd.x, a.x); c.y = fmaf(c.y, gd.y, a.y);
    c.z = fmaf(c.z, gd.z, a.z); c.w = fmaf(c.w, gd.w, a.w);
  }
}

// ---------- K4: per-event intensity replay with carried q-state ----------
__global__ __launch_bounds__(512, 4) void k_phase3(
    const int* __restrict__ mi, const float* __restrict__ alpha,
    const float* __restrict__ gamma, const float* __restrict__ mu,
    const float4* __restrict__ d4,
    const float4* __restrict__ Cl4, const float4* __restrict__ GP4,
    const float4* __restrict__ Dc4,
    float* __restrict__ npt, int N, int B)
{
  __shared__ float4 AT4[MT*MT];
  const int tid = threadIdx.x, lane = tid & 63;
  const float g0=gamma[0], g1=gamma[1], g2=gamma[2], g3=gamma[3];
  #pragma unroll
  for (int idx = tid; idx < MT*MT; idx += 512) {
    float a0=alpha[idx],         a1=alpha[MT*MT+idx];
    float a2=alpha[2*MT*MT+idx], a3=alpha[3*MT*MT+idx];
    AT4[idx] = make_float4(g0*a0, g1*a1, g2*a2, g3*a3);
  }
  __syncthreads();

  int b = __builtin_amdgcn_readfirstlane((int)blockIdx.x*8 + (tid >> 6));
  const int s0 = b*B, e0 = min(N, s0+B);
  const int g = b / GBC;
  float4 cl = Cl4[(size_t)b*64 + lane];
  float4 gp = GP4[(size_t)g*64 + lane];
  float4 dc = Dc4[b];                       // uniform
  float4 q;
  q.x = fmaf(gp.x, dc.x, cl.x); q.y = fmaf(gp.y, dc.y, cl.y);
  q.z = fmaf(gp.z, dc.z, cl.z); q.w = fmaf(gp.w, dc.w, cl.w);
  const float muL = mu[lane];
  float acc = 0.f;
  int i = s0;
  const int cnt = (e0 > s0) ? (e0 - s0) : 0;
  const int e4 = s0 + (cnt & ~3);
  for (; i < e4; i += 4) {
    int   mA=mi[i], mB=mi[i+1], mC=mi[i+2], mD=mi[i+3];
    float4 dA=d4[i], dB=d4[i+1], dC=d4[i+2], dD=d4[i+3];    // uniform s_loads
    float4 aA=AT4[(mA<<6)+lane], aB=AT4[(mB<<6)+lane];
    float4 aC=AT4[(mC<<6)+lane], aD=AT4[(mD<<6)+lane];
    float s;
    s = q.x*dA.x; s=fmaf(q.y,dA.y,s); s=fmaf(q.z,dA.z,s); s=fmaf(q.w,dA.w,s);
    acc += (lane == mA) ? __log2f(s + muL) : 0.f;
    q.x=fmaf(q.x,dA.x,aA.x); q.y=fmaf(q.y,dA.y,aA.y);
    q.z=fmaf(q.z,dA.z,aA.z); q.w=fmaf(q.w,dA.w,aA.w);
    s = q.x*dB.x; s=fmaf(q.y,dB.y,s); s=fmaf(q.z,dB.z,s); s=fmaf(q.w,dB.w,s);
    acc += (lane == mB) ? __log2f(s + muL) : 0.f;
    q.x=fmaf(q.x,dB.x,aB.x); q.y=fmaf(q.y,dB.y,aB.y);
    q.z=fmaf(q.z,dB.z,aB.z); q.w=fmaf(q.w,dB.w,aB.w);
    s = q.x*dC.x; s=fmaf(q.y,dC.y,s); s=fmaf(q.z,dC.z,s); s=fmaf(q.w,dC.w,s);
    acc += (lane == mC) ? __log2f(s + muL) : 0.f;
    q.x=fmaf(q.x,dC.x,aC.x); q.y=fmaf(q.y,dC.y,aC.y);
    q.z=fmaf(q.z,dC.z,aC.z); q.w=fmaf(q.w,dC.w,aC.w);
    s = q.x*dD.x; s=fmaf(q.y,dD.y,s); s=fmaf(q.z,dD.z,s); s=fmaf(q.w,dD.w,s);
    acc += (lane == mD) ? __log2f(s + muL) : 0.f;
    q.x=fmaf(q.x,dD.x,aD.x); q.y=fmaf(q.y,dD.y,aD.y);
    q.z=fmaf(q.z,dD.z,aD.z); q.w=fmaf(q.w,dD.w,aD.w);
  }
  for (; i < e0; ++i) {
    int m = mi[i];
    float4 d = d4[i];
    float4 a = AT4[(m<<6)+lane];
    float s = q.x*d.x; s=fmaf(q.y,d.y,s); s=fmaf(q.z,d.z,s); s=fmaf(q.w,d.w,s);
    acc += (lane == m) ? __log2f(s + muL) : 0.f;
    q.x=fmaf(q.x,d.x,a.x); q.y=fmaf(q.y,d.y,a.y);
    q.z=fmaf(q.z,d.z,a.z); q.w=fmaf(q.w,d.w,a.w);
  }
  float nll = wredf(acc);
  if (lane == 0) npt[b] = nll;
}

// ---------- K5: deterministic final reduction ----------
__global__ __launch_bounds__(512) void k_final(
    const float* __restrict__ mu, const int* __restrict__ Tp,
    const float* __restrict__ compP, int nc,
    const float* __restrict__ npt, int NB,
    float* __restrict__ out, int N)
{
  const int tid = threadIdx.x;
  double sc = 0.0, sn = 0.0;
  for (int i = tid; i < nc; i += 512) sc += (double)compP[i];
  for (int i = tid; i < NB; i += 512) sn += (double)npt[i];
  double sm = (tid < MT) ? (double)mu[tid] : 0.0;
  sc = wredd(sc); sn = wredd(sn); sm = wredd(sm);
  __shared__ double s3[3][8];
  const int wv = tid >> 6, lane = tid & 63;
  if (lane == 0) { s3[0][wv]=sc; s3[1][wv]=sn; s3[2][wv]=sm; }
  __syncthreads();
  if (tid == 0) {
    double C=0.0, L=0.0, Mm=0.0;
    #pragma unroll
    for (int j = 0; j < 8; ++j) { C+=s3[0][j]; L+=s3[1][j]; Mm+=s3[2][j]; }
    L *= 0.6931471805599453;   // acc was log2
    double T = (double)parse_T(Tp);
    out[0] = (float)((C + T*Mm - L) / (double)N);
  }
}

extern "C" void kernel_launch(void* const* d_in, const int* in_sizes, int n_in,
                              void* d_out, int out_size, void* d_ws, size_t ws_size,
                              hipStream_t stream)
{
  const float* mu    = (const float*)d_in[0];
  const float* alpha = (const float*)d_in[1];   // (K, M, M)
  const float* gamma = (const float*)d_in[2];   // (K,)
  const float* t     = (const float*)d_in[3];   // (N,)
  const int*   mi    = (const int*)d_in[4];     // (N,) int32
  const int*   Tp    = (const int*)d_in[5];     // scalar
  const int N = in_sizes[3];

  auto needF = [&](int nb) -> size_t {
    int ng = nb/GBC, nwg = nb/8;
    return (size_t)N*4 + (size_t)nb*256*2 + (size_t)nb*4*2
         + (size_t)ng*256*2 + (size_t)ng*4 + nwg + nb + 64;
  };
  int NB = 4096;
  while (NB > 256 && needF(NB)*4 > ws_size) NB >>= 1;
  const int B   = (N + NB - 1) / NB;
  const int NG  = NB / GBC;
  const int NWG = NB / 8;
  const int CH  = (N + NWG - 1) / NWG;

  float* p = (float*)d_ws;
  float4* d4    = (float4*)p; p += (size_t)N*4;
  float4* P4    = (float4*)p; p += (size_t)NB*256;
  float4* Cl4   = (float4*)p; p += (size_t)NB*256;
  float4* decf4 = (float4*)p; p += (size_t)NB*4;
  float4* Dc4   = (float4*)p; p += (size_t)NB*4;
  float4* Ag4   = (float4*)p; p += (size_t)NG*256;
  float4* GP4   = (float4*)p; p += (size_t)NG*256;
  float4* gdec4 = (float4*)p; p += (size_t)NG*4;
  float*  compP = p;          p += NWG;
  float*  npt   = p;          p += NB;

  k_phase1  <<<NWG,  512, 0, stream>>>(t, mi, alpha, gamma, Tp, d4, P4, decf4,
                                       compP, N, B, CH);
  k_scan    <<<NG/4, 256, 0, stream>>>(P4, decf4, Cl4, Dc4, Ag4, gdec4);
  k_scan_top<<<1,    64,  0, stream>>>(Ag4, gdec4, GP4, NG);
  k_phase3  <<<NWG,  512, 0, stream>>>(mi, alpha, gamma, mu, d4, Cl4, GP4, Dc4,
                                       npt, N, B);
  k_final   <<<1,    512, 0, stream>>>(mu, Tp, compP, NWG, npt, NB,
                                       (float*)d_out, N);
}

// Round 5
// 59.296 us; speedup vs baseline: 3.0108x; 1.7496x over previous
//
#include <hip/hip_runtime.h>

#define MT 64   // number of event types M
#define KK 4    // number of kernels K
#define GBC 16  // blocks per scan group
#define NSG 16  // groups per supergroup

// ---------- helpers ----------
__device__ __forceinline__ float wredf(float v) {
  #pragma unroll
  for (int off = 32; off > 0; off >>= 1) v += __shfl_xor(v, off, 64);
  return v;
}
__device__ __forceinline__ double wredd(double v) {
  #pragma unroll
  for (int off = 32; off > 0; off >>= 1) v += __shfl_xor(v, off, 64);
  return v;
}
// T arrives as a 1-element array; reference does jnp.float32(T).
__device__ __forceinline__ float parse_T(const int* Tp) {
  int v = *Tp;
  if (v >= 1 && v <= 1000000000) return (float)v;
  return __int_as_float(v);
}

// ---------- K1: d4 + compensator partials (thread/event) + block-local q-scan (wave/block) ----------
__global__ __launch_bounds__(512, 4) void k_phase1(
    const float* __restrict__ t, const int* __restrict__ mi,
    const float* __restrict__ alpha, const float* __restrict__ gamma,
    const int* __restrict__ Tp,
    float4* __restrict__ d4, float4* __restrict__ P4, float4* __restrict__ decf4,
    float* __restrict__ compP, int N, int B, int CH)
{
  __shared__ float4 AT4[MT*MT];   // AT4[m*64+n] = {gamma_k * alpha[k][m][n]}
  __shared__ float4 asumS[MT];    // asumS[m] = {sum_n alpha[k][m][n]}
  __shared__ float red[8];
  const int tid = threadIdx.x;
  const float g0=gamma[0], g1=gamma[1], g2=gamma[2], g3=gamma[3];
  #pragma unroll
  for (int idx = tid; idx < MT*MT; idx += 512) {
    float a0=alpha[idx],         a1=alpha[MT*MT+idx];
    float a2=alpha[2*MT*MT+idx], a3=alpha[3*MT*MT+idx];
    AT4[idx] = make_float4(g0*a0, g1*a1, g2*a2, g3*a3);
  }
  if (tid < MT*KK) {
    const int m = tid >> 2, k = tid & 3;
    const float4* row = (const float4*)(alpha + (size_t)k*MT*MT + m*MT);
    float s = 0.f;
    #pragma unroll
    for (int j = 0; j < MT/4; ++j) { float4 v = row[j]; s += (v.x+v.y)+(v.z+v.w); }
    ((float*)asumS)[(m<<2)+k] = s;
  }
  __syncthreads();

  // --- thread-per-event: decay factors + compensator ---
  const float T = parse_T(Tp);
  float comp = 0.f;
  {
    const int i0 = blockIdx.x * CH;
    const int i1 = min(N, i0 + CH);
    for (int i = i0 + tid; i < i1; i += 512) {
      float ti = t[i];
      float tp = (i > 0) ? t[i-1] : ti;
      float dt = ti - tp;
      d4[i] = make_float4(__expf(-g0*dt), __expf(-g1*dt),
                          __expf(-g2*dt), __expf(-g3*dt));
      int m = mi[i];
      float x = T - ti;
      float4 as = asumS[m];
      comp = fmaf(as.x, 1.f-__expf(-g0*x), comp);
      comp = fmaf(as.y, 1.f-__expf(-g1*x), comp);
      comp = fmaf(as.z, 1.f-__expf(-g2*x), comp);
      comp = fmaf(as.w, 1.f-__expf(-g3*x), comp);
    }
  }
  comp = wredf(comp);
  if ((tid & 63) == 0) red[tid >> 6] = comp;

  // --- wave-per-block local scan (own exps; d4 of other chunks not yet visible) ---
  const int lane = tid & 63;
  int b = __builtin_amdgcn_readfirstlane((int)blockIdx.x*8 + (tid >> 6));
  const int s0 = b*B, e0 = min(N, s0+B);
  float4 q = make_float4(0.f,0.f,0.f,0.f);
  if (s0 < e0) {
    float tprev = t[s0];
    int i = s0;
    const int e4 = s0 + ((e0 - s0) & ~3);
    for (; i < e4; i += 4) {
      float tA=t[i], tB=t[i+1], tC=t[i+2], tD=t[i+3];
      int   mA=mi[i], mB=mi[i+1], mC=mi[i+2], mD=mi[i+3];
      float4 aA=AT4[(mA<<6)+lane], aB=AT4[(mB<<6)+lane];
      float4 aC=AT4[(mC<<6)+lane], aD=AT4[(mD<<6)+lane];
      float dtA=tA-tprev, dtB=tB-tA, dtC=tC-tB, dtD=tD-tC; tprev=tD;
      float4 dA=make_float4(__expf(-g0*dtA),__expf(-g1*dtA),__expf(-g2*dtA),__expf(-g3*dtA));
      q.x=fmaf(q.x,dA.x,aA.x); q.y=fmaf(q.y,dA.y,aA.y);
      q.z=fmaf(q.z,dA.z,aA.z); q.w=fmaf(q.w,dA.w,aA.w);
      float4 dB=make_float4(__expf(-g0*dtB),__expf(-g1*dtB),__expf(-g2*dtB),__expf(-g3*dtB));
      q.x=fmaf(q.x,dB.x,aB.x); q.y=fmaf(q.y,dB.y,aB.y);
      q.z=fmaf(q.z,dB.z,aB.z); q.w=fmaf(q.w,dB.w,aB.w);
      float4 dC=make_float4(__expf(-g0*dtC),__expf(-g1*dtC),__expf(-g2*dtC),__expf(-g3*dtC));
      q.x=fmaf(q.x,dC.x,aC.x); q.y=fmaf(q.y,dC.y,aC.y);
      q.z=fmaf(q.z,dC.z,aC.z); q.w=fmaf(q.w,dC.w,aC.w);
      float4 dD=make_float4(__expf(-g0*dtD),__expf(-g1*dtD),__expf(-g2*dtD),__expf(-g3*dtD));
      q.x=fmaf(q.x,dD.x,aD.x); q.y=fmaf(q.y,dD.y,aD.y);
      q.z=fmaf(q.z,dD.z,aD.z); q.w=fmaf(q.w,dD.w,aD.w);
    }
    for (; i < e0; ++i) {
      float ti = t[i]; int m = mi[i];
      float dt = ti - tprev; tprev = ti;
      float4 a = AT4[(m<<6)+lane];
      float4 d = make_float4(__expf(-g0*dt),__expf(-g1*dt),__expf(-g2*dt),__expf(-g3*dt));
      q.x=fmaf(q.x,d.x,a.x); q.y=fmaf(q.y,d.y,a.y);
      q.z=fmaf(q.z,d.z,a.z); q.w=fmaf(q.w,d.w,a.w);
    }
  }
  P4[(size_t)b*64 + lane] = q;
  {
    int last  = max(e0-1, 0);
    int plast = min(max(s0-1, 0), N-1);
    float dtb = t[last] - t[plast];
    if (lane == 0)
      decf4[b] = make_float4(__expf(-g0*dtb),__expf(-g1*dtb),
                             __expf(-g2*dtb),__expf(-g3*dtb));
  }
  __syncthreads();
  if (tid == 0) {
    float c = 0.f;
    #pragma unroll
    for (int j = 0; j < 8; ++j) c += red[j];
    compP[blockIdx.x] = c;
  }
}

// ---------- K2 (L1): wave per group of GBC blocks, fully unrolled ----------
__global__ __launch_bounds__(64) void k_scan(
    const float4* __restrict__ P4, const float4* __restrict__ decf4,
    float4* __restrict__ Cl4, float4* __restrict__ Dc4,
    float4* __restrict__ Ag4, float4* __restrict__ gdec4)
{
  const int lane = threadIdx.x;
  const int g = blockIdx.x;
  float4 c  = make_float4(0.f,0.f,0.f,0.f);
  float4 dp = make_float4(1.f,1.f,1.f,1.f);
  const int b0 = g*GBC;
  #pragma unroll
  for (int j = 0; j < GBC; ++j) {
    const int b = b0 + j;
    Cl4[(size_t)b*64 + lane] = c;
    if (lane == 0) Dc4[b] = dp;
    float4 df = decf4[b];                   // uniform
    float4 p  = P4[(size_t)b*64 + lane];
    c.x = fmaf(c.x, df.x, p.x); c.y = fmaf(c.y, df.y, p.y);
    c.z = fmaf(c.z, df.z, p.z); c.w = fmaf(c.w, df.w, p.w);
    dp.x *= df.x; dp.y *= df.y; dp.z *= df.z; dp.w *= df.w;
  }
  Ag4[(size_t)g*64 + lane] = c;
  if (lane == 0) gdec4[g] = dp;
}

// ---------- K3 (L2+L3+fix): one workgroup, wave per supergroup ----------
// Pass A: within-super scan of group aggregates -> GP4 (partial), Gmd4 (prefix decay prod)
// Pass B: wave 0 scans the NSUP supergroup aggregates through LDS -> Tp
// Pass C: GP4[g] = Gm[g] + Gmd[g]*Tp[super(g)]   (final global carry into group g)
__global__ __launch_bounds__(1024) void k_scan2(
    const float4* __restrict__ Ag4, const float4* __restrict__ gdec4,
    float4* __restrict__ GP4, float4* __restrict__ Gmd4, int NSUP)
{
  __shared__ float4 SgL[NSG][64];
  __shared__ float4 TpL[NSG][64];
  __shared__ float4 sdecL[NSG];
  const int tid = threadIdx.x;
  const int wv = tid >> 6, lane = tid & 63;

  float4 c  = make_float4(0.f,0.f,0.f,0.f);
  float4 dp = make_float4(1.f,1.f,1.f,1.f);
  const int gBase = wv*NSG;
  #pragma unroll
  for (int j = 0; j < NSG; ++j) {
    const int g = gBase + j;
    GP4[(size_t)g*64 + lane] = c;           // within-super carry (fixed in pass C)
    if (lane == 0) Gmd4[g] = dp;
    float4 gd = gdec4[g];                   // uniform
    float4 a  = Ag4[(size_t)g*64 + lane];
    c.x = fmaf(c.x, gd.x, a.x); c.y = fmaf(c.y, gd.y, a.y);
    c.z = fmaf(c.z, gd.z, a.z); c.w = fmaf(c.w, gd.w, a.w);
    dp.x *= gd.x; dp.y *= gd.y; dp.z *= gd.z; dp.w *= gd.w;
  }
  SgL[wv][lane] = c;
  if (lane == 0) sdecL[wv] = dp;
  __syncthreads();

  if (wv == 0) {
    float4 tc = make_float4(0.f,0.f,0.f,0.f);
    for (int s = 0; s < NSUP; ++s) {
      TpL[s][lane] = tc;
      float4 sd = sdecL[s];
      float4 a  = SgL[s][lane];
      tc.x = fmaf(tc.x, sd.x, a.x); tc.y = fmaf(tc.y, sd.y, a.y);
      tc.z = fmaf(tc.z, sd.z, a.z); tc.w = fmaf(tc.w, sd.w, a.w);
    }
  }
  __syncthreads();

  const float4 tp = TpL[wv][lane];
  #pragma unroll
  for (int j = 0; j < NSG; ++j) {
    const int g = gBase + j;
    float4 gm  = GP4[(size_t)g*64 + lane];  // re-read own writes (same thread)
    float4 gmd = Gmd4[g];                   // uniform
    gm.x = fmaf(gmd.x, tp.x, gm.x); gm.y = fmaf(gmd.y, tp.y, gm.y);
    gm.z = fmaf(gmd.z, tp.z, gm.z); gm.w = fmaf(gmd.w, tp.w, gm.w);
    GP4[(size_t)g*64 + lane] = gm;
  }
}

// ---------- K4: per-event intensity replay with carried q-state ----------
__global__ __launch_bounds__(512, 4) void k_phase3(
    const int* __restrict__ mi, const float* __restrict__ alpha,
    const float* __restrict__ gamma, const float* __restrict__ mu,
    const float4* __restrict__ d4,
    const float4* __restrict__ Cl4, const float4* __restrict__ GP4,
    const float4* __restrict__ Dc4,
    float* __restrict__ npt, int N, int B)
{
  __shared__ float4 AT4[MT*MT];
  const int tid = threadIdx.x, lane = tid & 63;
  const float g0=gamma[0], g1=gamma[1], g2=gamma[2], g3=gamma[3];
  #pragma unroll
  for (int idx = tid; idx < MT*MT; idx += 512) {
    float a0=alpha[idx],         a1=alpha[MT*MT+idx];
    float a2=alpha[2*MT*MT+idx], a3=alpha[3*MT*MT+idx];
    AT4[idx] = make_float4(g0*a0, g1*a1, g2*a2, g3*a3);
  }
  __syncthreads();

  int b = __builtin_amdgcn_readfirstlane((int)blockIdx.x*8 + (tid >> 6));
  const int s0 = b*B, e0 = min(N, s0+B);
  const int g = b / GBC;
  float4 cl = Cl4[(size_t)b*64 + lane];
  float4 gp = GP4[(size_t)g*64 + lane];
  float4 dc = Dc4[b];                       // uniform
  float4 q;
  q.x = fmaf(gp.x, dc.x, cl.x); q.y = fmaf(gp.y, dc.y, cl.y);
  q.z = fmaf(gp.z, dc.z, cl.z); q.w = fmaf(gp.w, dc.w, cl.w);
  const float muL = mu[lane];
  float acc = 0.f;
  int i = s0;
  const int cnt = (e0 > s0) ? (e0 - s0) : 0;
  const int e4 = s0 + (cnt & ~3);
  for (; i < e4; i += 4) {
    int   mA=mi[i], mB=mi[i+1], mC=mi[i+2], mD=mi[i+3];
    float4 dA=d4[i], dB=d4[i+1], dC=d4[i+2], dD=d4[i+3];    // uniform s_loads
    float4 aA=AT4[(mA<<6)+lane], aB=AT4[(mB<<6)+lane];
    float4 aC=AT4[(mC<<6)+lane], aD=AT4[(mD<<6)+lane];
    float s;
    s = q.x*dA.x; s=fmaf(q.y,dA.y,s); s=fmaf(q.z,dA.z,s); s=fmaf(q.w,dA.w,s);
    acc += (lane == mA) ? __log2f(s + muL) : 0.f;
    q.x=fmaf(q.x,dA.x,aA.x); q.y=fmaf(q.y,dA.y,aA.y);
    q.z=fmaf(q.z,dA.z,aA.z); q.w=fmaf(q.w,dA.w,aA.w);
    s = q.x*dB.x; s=fmaf(q.y,dB.y,s); s=fmaf(q.z,dB.z,s); s=fmaf(q.w,dB.w,s);
    acc += (lane == mB) ? __log2f(s + muL) : 0.f;
    q.x=fmaf(q.x,dB.x,aB.x); q.y=fmaf(q.y,dB.y,aB.y);
    q.z=fmaf(q.z,dB.z,aB.z); q.w=fmaf(q.w,dB.w,aB.w);
    s = q.x*dC.x; s=fmaf(q.y,dC.y,s); s=fmaf(q.z,dC.z,s); s=fmaf(q.w,dC.w,s);
    acc += (lane == mC) ? __log2f(s + muL) : 0.f;
    q.x=fmaf(q.x,dC.x,aC.x); q.y=fmaf(q.y,dC.y,aC.y);
    q.z=fmaf(q.z,dC.z,aC.z); q.w=fmaf(q.w,dC.w,aC.w);
    s = q.x*dD.x; s=fmaf(q.y,dD.y,s); s=fmaf(q.z,dD.z,s); s=fmaf(q.w,dD.w,s);
    acc += (lane == mD) ? __log2f(s + muL) : 0.f;
    q.x=fmaf(q.x,dD.x,aD.x); q.y=fmaf(q.y,dD.y,aD.y);
    q.z=fmaf(q.z,dD.z,aD.z); q.w=fmaf(q.w,dD.w,aD.w);
  }
  for (; i < e0; ++i) {
    int m = mi[i];
    float4 d = d4[i];
    float4 a = AT4[(m<<6)+lane];
    float s = q.x*d.x; s=fmaf(q.y,d.y,s); s=fmaf(q.z,d.z,s); s=fmaf(q.w,d.w,s);
    acc += (lane == m) ? __log2f(s + muL) : 0.f;
    q.x=fmaf(q.x,d.x,a.x); q.y=fmaf(q.y,d.y,a.y);
    q.z=fmaf(q.z,d.z,a.z); q.w=fmaf(q.w,d.w,a.w);
  }
  float nll = wredf(acc);
  if (lane == 0) npt[b] = nll;
}

// ---------- K5: deterministic final reduction ----------
__global__ __launch_bounds__(512) void k_final(
    const float* __restrict__ mu, const int* __restrict__ Tp,
    const float* __restrict__ compP, int nc,
    const float* __restrict__ npt, int NB,
    float* __restrict__ out, int N)
{
  const int tid = threadIdx.x;
  double sc = 0.0, sn = 0.0;
  for (int i = tid; i < nc; i += 512) sc += (double)compP[i];
  for (int i = tid; i < NB; i += 512) sn += (double)npt[i];
  double sm = (tid < MT) ? (double)mu[tid] : 0.0;
  sc = wredd(sc); sn = wredd(sn); sm = wredd(sm);
  __shared__ double s3[3][8];
  const int wv = tid >> 6, lane = tid & 63;
  if (lane == 0) { s3[0][wv]=sc; s3[1][wv]=sn; s3[2][wv]=sm; }
  __syncthreads();
  if (tid == 0) {
    double C=0.0, L=0.0, Mm=0.0;
    #pragma unroll
    for (int j = 0; j < 8; ++j) { C+=s3[0][j]; L+=s3[1][j]; Mm+=s3[2][j]; }
    L *= 0.6931471805599453;   // acc was log2
    double T = (double)parse_T(Tp);
    out[0] = (float)((C + T*Mm - L) / (double)N);
  }
}

extern "C" void kernel_launch(void* const* d_in, const int* in_sizes, int n_in,
                              void* d_out, int out_size, void* d_ws, size_t ws_size,
                              hipStream_t stream)
{
  const float* mu    = (const float*)d_in[0];
  const float* alpha = (const float*)d_in[1];   // (K, M, M)
  const float* gamma = (const float*)d_in[2];   // (K,)
  const float* t     = (const float*)d_in[3];   // (N,)
  const int*   mi    = (const int*)d_in[4];     // (N,) int32
  const int*   Tp    = (const int*)d_in[5];     // scalar
  const int N = in_sizes[3];

  auto needF = [&](int nb) -> size_t {
    int ng = nb/GBC, nwg = nb/8;
    return (size_t)N*4 + (size_t)nb*256*2 + (size_t)nb*4*2
         + (size_t)ng*256*2 + (size_t)ng*4*2 + nwg + nb + 64;
  };
  int NB = 4096;                 // = GBC * NSG * NSUP; keep divisible by 256
  while (NB > 256 && needF(NB)*4 > ws_size) NB >>= 1;
  const int B    = (N + NB - 1) / NB;
  const int NG   = NB / GBC;
  const int NSUP = NG / NSG;     // 16 at NB=4096
  const int NWG  = NB / 8;
  const int CH   = (N + NWG - 1) / NWG;

  float* p = (float*)d_ws;
  float4* d4    = (float4*)p; p += (size_t)N*4;
  float4* P4    = (float4*)p; p += (size_t)NB*256;
  float4* Cl4   = (float4*)p; p += (size_t)NB*256;
  float4* decf4 = (float4*)p; p += (size_t)NB*4;
  float4* Dc4   = (float4*)p; p += (size_t)NB*4;
  float4* Ag4   = (float4*)p; p += (size_t)NG*256;
  float4* GP4   = (float4*)p; p += (size_t)NG*256;
  float4* gdec4 = (float4*)p; p += (size_t)NG*4;
  float4* Gmd4  = (float4*)p; p += (size_t)NG*4;
  float*  compP = p;          p += NWG;
  float*  npt   = p;          p += NB;

  k_phase1<<<NWG,  512,       0, stream>>>(t, mi, alpha, gamma, Tp, d4, P4, decf4,
                                           compP, N, B, CH);
  k_scan  <<<NG,   64,        0, stream>>>(P4, decf4, Cl4, Dc4, Ag4, gdec4);
  k_scan2 <<<1,    NSUP*64,   0, stream>>>(Ag4, gdec4, GP4, Gmd4, NSUP);
  k_phase3<<<NWG,  512,       0, stream>>>(mi, alpha, gamma, mu, d4, Cl4, GP4, Dc4,
                                           npt, N, B);
  k_final <<<1,    512,       0, stream>>>(mu, Tp, compP, NWG, npt, NB,
                                           (float*)d_out, N);
}

// Round 6
// 48.461 us; speedup vs baseline: 3.6840x; 1.2236x over previous
//
#include <hip/hip_runtime.h>

#define MT 64     // number of event types M
#define KK 4      // number of kernels K
#define MAXB 64   // max events per scan-block supported by LDS tiles (N <= 8*MAXB*NWG)

// ---------- helpers ----------
__device__ __forceinline__ float wredf(float v) {
  #pragma unroll
  for (int off = 32; off > 0; off >>= 1) v += __shfl_xor(v, off, 64);
  return v;
}
__device__ __forceinline__ double wredd(double v) {
  #pragma unroll
  for (int off = 32; off > 0; off >>= 1) v += __shfl_xor(v, off, 64);
  return v;
}
__device__ __forceinline__ float4 f4fma(float4 a, float4 b, float4 c) { // a*b+c
  return make_float4(fmaf(a.x,b.x,c.x), fmaf(a.y,b.y,c.y),
                     fmaf(a.z,b.z,c.z), fmaf(a.w,b.w,c.w));
}
__device__ __forceinline__ float4 f4mul(float4 a, float4 b) {
  return make_float4(a.x*b.x, a.y*b.y, a.z*b.z, a.w*b.w);
}
// T arrives as a 1-element array; reference does jnp.float32(T).
__device__ __forceinline__ float parse_T(const int* Tp) {
  int v = *Tp;
  if (v >= 1 && v <= 1000000000) return (float)v;
  return __int_as_float(v);
}

// ---------- K1: d4-tile + compensator + block-local q-scan + intra-WG octet scan ----------
// WG = 8 waves = 8 consecutive blocks ("octet"). Emits per-block Cl8/Dc8 (carry within
// octet) and per-octet Ag/gdec for the middle scan. No global d4, no exp in serial loop.
__global__ __launch_bounds__(512, 4) void k_phase1(
    const float* __restrict__ t, const int* __restrict__ mi,
    const float* __restrict__ alpha, const float* __restrict__ gamma,
    const int* __restrict__ Tp,
    float4* __restrict__ Cl8, float4* __restrict__ Dc8,
    float4* __restrict__ Ag, float4* __restrict__ gdec,
    float* __restrict__ compP, int N, int B)
{
  __shared__ float4 AT4[MT*MT];    // AT4[m*64+n] = {gamma_k*alpha[k][m][n]}
  __shared__ float4 asumS[MT];     // asumS[m]   = {sum_n alpha[k][m][n]}
  __shared__ float red[8];
  __shared__ __align__(16) unsigned char upool[8*MAXB*16 + 8*MAXB*4]; // d4t+miL / cw+cwd
  float4* d4t = (float4*)upool;                  // [8*MAXB] decay factors (this WG's events)
  int*    miL = (int*)(upool + 8*MAXB*16);       // [8*MAXB] event types
  float4* cw  = (float4*)upool;                  // [8][64]  cross-wave scan area (reuse)
  float4* cwd = (float4*)(upool + 8192);         // [8]      per-block decay factors

  const int tid = threadIdx.x, lane = tid & 63, wv = tid >> 6;
  const float g0=gamma[0], g1=gamma[1], g2=gamma[2], g3=gamma[3];

  // stage tables
  #pragma unroll
  for (int idx = tid; idx < MT*MT; idx += 512) {
    float a0=alpha[idx],         a1=alpha[MT*MT+idx];
    float a2=alpha[2*MT*MT+idx], a3=alpha[3*MT*MT+idx];
    AT4[idx] = make_float4(g0*a0, g1*a1, g2*a2, g3*a3);
  }
  if (tid < MT*KK) {
    const int m = tid >> 2, k = tid & 3;
    const float4* row = (const float4*)(alpha + (size_t)k*MT*MT + m*MT);
    float s = 0.f;
    #pragma unroll
    for (int j = 0; j < MT/4; ++j) { float4 v = row[j]; s += (v.x+v.y)+(v.z+v.w); }
    ((float*)asumS)[(m<<2)+k] = s;
  }
  __syncthreads();

  // parallel part: d4 tile + mi tile + compensator (one event per thread)
  const float T = parse_T(Tp);
  const int s0w = (int)blockIdx.x * 8 * B;
  const int BPW = 8 * B;
  float comp = 0.f;
  for (int j = tid; j < BPW; j += 512) {
    const int i = s0w + j;
    if (i < N) {
      float ti = t[i];
      float tp = (i > 0) ? t[i-1] : ti;
      float dt = ti - tp;
      d4t[j] = make_float4(__expf(-g0*dt), __expf(-g1*dt),
                           __expf(-g2*dt), __expf(-g3*dt));
      int m = mi[i];
      miL[j] = m;
      float x = T - ti;
      float4 as = asumS[m];
      comp = fmaf(as.x, 1.f-__expf(-g0*x), comp);
      comp = fmaf(as.y, 1.f-__expf(-g1*x), comp);
      comp = fmaf(as.z, 1.f-__expf(-g2*x), comp);
      comp = fmaf(as.w, 1.f-__expf(-g3*x), comp);
    }
  }
  comp = wredf(comp);
  if (lane == 0) red[wv] = comp;
  __syncthreads();
  if (tid == 0) {
    float c = 0.f;
    #pragma unroll
    for (int j = 0; j < 8; ++j) c += red[j];
    compP[blockIdx.x] = c;
  }

  // wave-per-block serial scan (reads LDS only; zero transcendentals)
  const int b  = (int)blockIdx.x*8 + wv;
  const int s0 = b*B, e0 = min(N, s0+B);
  float4 q = make_float4(0.f,0.f,0.f,0.f);
  {
    int j = wv*B;
    #pragma unroll 4
    for (int i = s0; i < e0; ++i, ++j) {
      float4 d = d4t[j];                 // wave-uniform LDS broadcast
      int m = miL[j];                    // wave-uniform
      float4 a = AT4[(m<<6) + lane];     // 1KB/wave contiguous, conflict-free
      q = f4fma(q, d, a);
    }
  }
  // per-block decay factor (lane 0)
  float4 df = make_float4(1.f,1.f,1.f,1.f);
  if (lane == 0) {
    int last  = max(e0-1, 0);
    int plast = min(max(s0-1, 0), N-1);
    float dtb = t[last] - t[plast];
    df = make_float4(__expf(-g0*dtb),__expf(-g1*dtb),
                     __expf(-g2*dtb),__expf(-g3*dtb));
  }
  __syncthreads();                       // all d4t/miL reads done; safe to reuse pool
  cw[wv*64 + lane] = q;
  if (lane == 0) cwd[wv] = df;
  __syncthreads();

  // intra-octet cross-wave scan (8 steps in LDS, every wave replays it)
  float4 c  = make_float4(0.f,0.f,0.f,0.f);
  float4 dp = make_float4(1.f,1.f,1.f,1.f);
  float4 Cl = c, Dc = dp;
  #pragma unroll
  for (int j = 0; j < 8; ++j) {
    if (j == wv) { Cl = c; Dc = dp; }
    float4 d = cwd[j];
    float4 P = cw[j*64 + lane];
    c  = f4fma(c, d, P);
    dp = f4mul(dp, d);
  }
  Cl8[(size_t)b*64 + lane] = Cl;
  if (lane == 0) Dc8[b] = Dc;
  if (wv == 0) {
    Ag[(size_t)blockIdx.x*64 + lane] = c;
    if (lane == 0) gdec[blockIdx.x] = dp;
  }
}

// ---------- K2: middle scan over octets (1 WG, NW waves x 32 octets) ----------
// Emits GPp (within-super carry), Gmd (prefix decay product), Top (super carries).
__global__ __launch_bounds__(1024) void k_scan2(
    const float4* __restrict__ Ag, const float4* __restrict__ gdec,
    float4* __restrict__ GPp, float4* __restrict__ Gmd, float4* __restrict__ Top,
    int NW)
{
  __shared__ float4 SgL[16*64];
  __shared__ float4 sdec[16];
  const int tid = threadIdx.x, lane = tid & 63, W = tid >> 6;
  float4 c  = make_float4(0.f,0.f,0.f,0.f);
  float4 dp = make_float4(1.f,1.f,1.f,1.f);
  const int base = W*32;
  #pragma unroll 4
  for (int j = 0; j < 32; ++j) {
    const int oct = base + j;
    GPp[(size_t)oct*64 + lane] = c;
    if (lane == 0) Gmd[oct] = dp;
    float4 gd = gdec[oct];               // uniform
    float4 a  = Ag[(size_t)oct*64 + lane];
    c  = f4fma(c, gd, a);
    dp = f4mul(dp, gd);
  }
  SgL[W*64 + lane] = c;
  if (lane == 0) sdec[W] = dp;
  __syncthreads();
  if (W == 0) {
    float4 tc = make_float4(0.f,0.f,0.f,0.f);
    for (int s = 0; s < NW; ++s) {
      Top[(size_t)s*64 + lane] = tc;
      float4 sd = sdec[s];
      float4 a  = SgL[s*64 + lane];
      tc = f4fma(tc, sd, a);
    }
  }
}

// ---------- K3: per-event intensity replay with 2-level carried q-state ----------
__global__ __launch_bounds__(512, 4) void k_phase3(
    const float* __restrict__ t, const int* __restrict__ mi,
    const float* __restrict__ alpha, const float* __restrict__ gamma,
    const float* __restrict__ mu,
    const float4* __restrict__ Cl8, const float4* __restrict__ Dc8,
    const float4* __restrict__ GPp, const float4* __restrict__ Gmd,
    const float4* __restrict__ Top,
    float* __restrict__ npt, int N, int B)
{
  __shared__ float4 AT4[MT*MT];
  __shared__ float4 d4t[8*MAXB];
  __shared__ int    miL[8*MAXB];
  const int tid = threadIdx.x, lane = tid & 63, wv = tid >> 6;
  const float g0=gamma[0], g1=gamma[1], g2=gamma[2], g3=gamma[3];

  #pragma unroll
  for (int idx = tid; idx < MT*MT; idx += 512) {
    float a0=alpha[idx],         a1=alpha[MT*MT+idx];
    float a2=alpha[2*MT*MT+idx], a3=alpha[3*MT*MT+idx];
    AT4[idx] = make_float4(g0*a0, g1*a1, g2*a2, g3*a3);
  }
  const int s0w = (int)blockIdx.x * 8 * B;
  const int BPW = 8 * B;
  for (int j = tid; j < BPW; j += 512) {
    const int i = s0w + j;
    if (i < N) {
      float ti = t[i];
      float tp = (i > 0) ? t[i-1] : ti;
      float dt = ti - tp;
      d4t[j] = make_float4(__expf(-g0*dt), __expf(-g1*dt),
                           __expf(-g2*dt), __expf(-g3*dt));
      miL[j] = mi[i];
    }
  }
  __syncthreads();

  const int b  = (int)blockIdx.x*8 + wv;
  const int s0 = b*B, e0 = min(N, s0+B);
  const int oct = blockIdx.x, sup = oct >> 5;
  // q = Cl8 + Dc8*(GPp + Gmd*Top)
  float4 cl = Cl8[(size_t)b*64 + lane];
  float4 gp = GPp[(size_t)oct*64 + lane];
  float4 tp4 = Top[(size_t)sup*64 + lane];
  float4 Dc = Dc8[b];                    // uniform
  float4 gm = Gmd[oct];                  // uniform
  float4 q = f4fma(Dc, f4fma(gm, tp4, gp), cl);

  const float muL = mu[lane];
  float acc = 0.f;
  {
    int j = wv*B;
    #pragma unroll 4
    for (int i = s0; i < e0; ++i, ++j) {
      float4 d = d4t[j];                 // wave-uniform
      int m = miL[j];                    // wave-uniform
      float4 a = AT4[(m<<6) + lane];
      float s = q.x*d.x; s=fmaf(q.y,d.y,s); s=fmaf(q.z,d.z,s); s=fmaf(q.w,d.w,s);
      acc += (lane == m) ? __log2f(s + muL) : 0.f;
      q = f4fma(q, d, a);
    }
  }
  float nll = wredf(acc);
  if (lane == 0) npt[b] = nll;
}

// ---------- K4: deterministic final reduction ----------
__global__ __launch_bounds__(512) void k_final(
    const float* __restrict__ mu, const int* __restrict__ Tp,
    const float* __restrict__ compP, int nc,
    const float* __restrict__ npt, int NB,
    float* __restrict__ out, int N)
{
  const int tid = threadIdx.x;
  double sc = 0.0, sn = 0.0;
  for (int i = tid; i < nc; i += 512) sc += (double)compP[i];
  for (int i = tid; i < NB; i += 512) sn += (double)npt[i];
  double sm = (tid < MT) ? (double)mu[tid] : 0.0;
  sc = wredd(sc); sn = wredd(sn); sm = wredd(sm);
  __shared__ double s3[3][8];
  const int wv = tid >> 6, lane = tid & 63;
  if (lane == 0) { s3[0][wv]=sc; s3[1][wv]=sn; s3[2][wv]=sm; }
  __syncthreads();
  if (tid == 0) {
    double C=0.0, L=0.0, Mm=0.0;
    #pragma unroll
    for (int j = 0; j < 8; ++j) { C+=s3[0][j]; L+=s3[1][j]; Mm+=s3[2][j]; }
    L *= 0.6931471805599453;             // acc was log2
    double T = (double)parse_T(Tp);
    out[0] = (float)((C + T*Mm - L) / (double)N);
  }
}

extern "C" void kernel_launch(void* const* d_in, const int* in_sizes, int n_in,
                              void* d_out, int out_size, void* d_ws, size_t ws_size,
                              hipStream_t stream)
{
  const float* mu    = (const float*)d_in[0];
  const float* alpha = (const float*)d_in[1];   // (K, M, M)
  const float* gamma = (const float*)d_in[2];   // (K,)
  const float* t     = (const float*)d_in[3];   // (N,)
  const int*   mi    = (const int*)d_in[4];     // (N,) int32
  const int*   Tp    = (const int*)d_in[5];     // scalar
  const int N = in_sizes[3];

  // NB blocks; B = events/block (<= MAXB for N <= 262144); octet = 8 blocks = 1 WG
  int NB = 4096;                                // multiple of 256 -> NOG multiple of 32
  const int B   = (N + NB - 1) / NB;            // 49 at N=200k
  const int NOG = NB / 8;                       // 512 octets
  const int NW  = NOG / 32;                     // 16 waves in k_scan2

  float* p = (float*)d_ws;
  float4* Cl8   = (float4*)p; p += (size_t)NB*256;   // carry within octet, per block
  float4* Ag    = (float4*)p; p += (size_t)NOG*256;  // octet aggregates
  float4* GPp   = (float4*)p; p += (size_t)NOG*256;  // within-super carry, per octet
  float4* Top   = (float4*)p; p += (size_t)16*256;   // super carries
  float4* Dc8   = (float4*)p; p += (size_t)NB*4;     // decay prefix within octet
  float4* gdec  = (float4*)p; p += (size_t)NOG*4;    // octet decay products
  float4* Gmd   = (float4*)p; p += (size_t)NOG*4;    // decay prefix within super
  float*  compP = p;          p += NOG;              // compensator partials (per WG)
  float*  npt   = p;          p += NB;               // nll partials (per block)

  k_phase1<<<NOG, 512,   0, stream>>>(t, mi, alpha, gamma, Tp, Cl8, Dc8, Ag, gdec,
                                      compP, N, B);
  k_scan2 <<<1,   NW*64, 0, stream>>>(Ag, gdec, GPp, Gmd, Top, NW);
  k_phase3<<<NOG, 512,   0, stream>>>(t, mi, alpha, gamma, mu, Cl8, Dc8, GPp, Gmd,
                                      Top, npt, N, B);
  k_final <<<1,   512,   0, stream>>>(mu, Tp, compP, NOG, npt, NB,
                                      (float*)d_out, N);
}